// Round 1
// baseline (654.860 us; speedup 1.0000x reference)
//
#include <hip/hip_runtime.h>
#include <hip/hip_bf16.h>
#include <math.h>

#define N_NODES 50000
#define N_EDGES 640000
#define DIM 128
#define NLAYER 3
#define NEG_SLOPE 0.2f
#define LN_EPS 1e-5f

// ---------------- CSR build ----------------

__global__ void hist_kernel(const int* __restrict__ dst, int* __restrict__ deg) {
    int e = blockIdx.x * blockDim.x + threadIdx.x;
    if (e < N_EDGES) atomicAdd(&deg[dst[e]], 1);
}

__global__ __launch_bounds__(1024) void scan_kernel(const int* __restrict__ deg,
                                                    int* __restrict__ rowptr) {
    __shared__ int sdata[1024];
    int t = threadIdx.x;
    int carry = 0;
    if (t == 0) rowptr[0] = 0;
    for (int base = 0; base < N_NODES; base += 1024) {
        int idx = base + t;
        int v = (idx < N_NODES) ? deg[idx] : 0;
        sdata[t] = v;
        __syncthreads();
        for (int off = 1; off < 1024; off <<= 1) {
            int add = (t >= off) ? sdata[t - off] : 0;
            __syncthreads();
            sdata[t] += add;
            __syncthreads();
        }
        if (idx < N_NODES) rowptr[idx + 1] = carry + sdata[t];
        carry += sdata[1023];
        __syncthreads();
    }
}

__global__ void scatter_kernel(const int* __restrict__ src, const int* __restrict__ dst,
                               const int* __restrict__ rowptr, int* __restrict__ cnt,
                               int* __restrict__ esrc) {
    int e = blockIdx.x * blockDim.x + threadIdx.x;
    if (e < N_EDGES) {
        int d = dst[e];
        int pos = rowptr[d] + atomicAdd(&cnt[d], 1);
        esrc[pos] = src[e];
    }
}

// ---------------- fused dual GEMM: xl = x@Wl+bl, xr = x@Wr+br ----------------
// block = 256 threads, 64 rows per block. LDS-staged x tile, W streamed via L1/L2.

__global__ __launch_bounds__(256) void gemm_kernel(
    const float* __restrict__ x,
    const float* __restrict__ Wl, const float* __restrict__ bl,
    const float* __restrict__ Wr, const float* __restrict__ br,
    float* __restrict__ xl, float* __restrict__ xr)
{
    __shared__ float xs[64][129];   // pad 129: 8-row stride -> 2-way bank alias (free)
    int t = threadIdx.x;
    int rowbase = blockIdx.x * 64;

    #pragma unroll
    for (int i = 0; i < 32; ++i) {
        int idx = i * 256 + t;
        int r = idx >> 7, c = idx & 127;
        int gr = rowbase + r;
        xs[r][c] = (gr < N_NODES) ? x[gr * DIM + c] : 0.0f;
    }
    __syncthreads();

    int cg = (t & 31) * 4;     // output col base (0..124)
    int rg = (t >> 5) * 8;     // row base within tile (0..56)

    float accl[8][4], accr[8][4];
    #pragma unroll
    for (int r = 0; r < 8; ++r)
        #pragma unroll
        for (int c = 0; c < 4; ++c) { accl[r][c] = 0.f; accr[r][c] = 0.f; }

    #pragma unroll 4
    for (int k = 0; k < 128; ++k) {
        float4 wl = *reinterpret_cast<const float4*>(&Wl[k * DIM + cg]);
        float4 wr = *reinterpret_cast<const float4*>(&Wr[k * DIM + cg]);
        #pragma unroll
        for (int r = 0; r < 8; ++r) {
            float a = xs[rg + r][k];
            accl[r][0] += a * wl.x; accl[r][1] += a * wl.y;
            accl[r][2] += a * wl.z; accl[r][3] += a * wl.w;
            accr[r][0] += a * wr.x; accr[r][1] += a * wr.y;
            accr[r][2] += a * wr.z; accr[r][3] += a * wr.w;
        }
    }

    float4 bl4 = *reinterpret_cast<const float4*>(&bl[cg]);
    float4 br4 = *reinterpret_cast<const float4*>(&br[cg]);
    #pragma unroll
    for (int r = 0; r < 8; ++r) {
        int gr = rowbase + rg + r;
        if (gr < N_NODES) {
            float4 ol, orr;
            ol.x = accl[r][0] + bl4.x; ol.y = accl[r][1] + bl4.y;
            ol.z = accl[r][2] + bl4.z; ol.w = accl[r][3] + bl4.w;
            orr.x = accr[r][0] + br4.x; orr.y = accr[r][1] + br4.y;
            orr.z = accr[r][2] + br4.z; orr.w = accr[r][3] + br4.w;
            *reinterpret_cast<float4*>(&xl[gr * DIM + cg]) = ol;
            *reinterpret_cast<float4*>(&xr[gr * DIM + cg]) = orr;
        }
    }
}

// ---------------- fused edge aggregation + softmax + bias/relu + LN + residual ----
// one wave (64 lanes) per dst node; lane l owns channels 2l, 2l+1.

__global__ __launch_bounds__(256) void agg_kernel(
    const float* __restrict__ xl, const float* __restrict__ xr,
    const int* __restrict__ esrc, const int* __restrict__ rowptr,
    const float* __restrict__ att, const float* __restrict__ bias,
    const float* __restrict__ gamma, const float* __restrict__ beta,
    float* __restrict__ cur)
{
    int node = blockIdx.x * 4 + (threadIdx.x >> 6);
    int lane = threadIdx.x & 63;
    if (node >= N_NODES) return;

    float2 xri  = *reinterpret_cast<const float2*>(&xr[node * DIM + 2 * lane]);
    float2 att2 = *reinterpret_cast<const float2*>(&att[2 * lane]);

    float m = -1e30f, s = 0.f;
    float ox = 0.f, oy = 0.f;

    int e0 = rowptr[node], e1 = rowptr[node + 1];
    for (int e = e0; e < e1; ++e) {
        int j = esrc[e];
        float2 v = *reinterpret_cast<const float2*>(&xl[j * DIM + 2 * lane]);
        float tx = v.x + xri.x, ty = v.y + xri.y;
        tx = tx > 0.f ? tx : NEG_SLOPE * tx;
        ty = ty > 0.f ? ty : NEG_SLOPE * ty;
        float p = tx * att2.x + ty * att2.y;
        // reduce within each 16-lane (per-head) group
        p += __shfl_xor(p, 1);
        p += __shfl_xor(p, 2);
        p += __shfl_xor(p, 4);
        p += __shfl_xor(p, 8);
        float nm = fmaxf(m, p);
        float sc = __expf(m - nm);
        float w  = __expf(p - nm);
        s  = s * sc + w;
        ox = ox * sc + w * v.x;
        oy = oy * sc + w * v.y;
        m = nm;
    }

    float inv = 1.f / (s + 1e-16f);
    float2 b2 = *reinterpret_cast<const float2*>(&bias[2 * lane]);
    float gx = fmaxf(ox * inv + b2.x, 0.f);
    float gy = fmaxf(oy * inv + b2.y, 0.f);

    // LayerNorm over 128 channels (full-wave reduce)
    float sum = gx + gy;
    #pragma unroll
    for (int off = 1; off < 64; off <<= 1) sum += __shfl_xor(sum, off);
    float mu = sum * (1.f / 128.f);
    float dx = gx - mu, dy = gy - mu;
    float ss = dx * dx + dy * dy;
    #pragma unroll
    for (int off = 1; off < 64; off <<= 1) ss += __shfl_xor(ss, off);
    float rstd = rsqrtf(ss * (1.f / 128.f) + LN_EPS);

    float2 g2  = *reinterpret_cast<const float2*>(&gamma[2 * lane]);
    float2 be2 = *reinterpret_cast<const float2*>(&beta[2 * lane]);
    float2 c2  = *reinterpret_cast<const float2*>(&cur[node * DIM + 2 * lane]);
    float yx = dx * rstd * g2.x + be2.x + c2.x;
    float yy = dy * rstd * g2.y + be2.y + c2.y;
    *reinterpret_cast<float2*>(&cur[node * DIM + 2 * lane]) = make_float2(yx, yy);
}

// ---------------- launch ----------------

extern "C" void kernel_launch(void* const* d_in, const int* in_sizes, int n_in,
                              void* d_out, int out_size, void* d_ws, size_t ws_size,
                              hipStream_t stream) {
    const float* x     = (const float*)d_in[0];
    const int*   ei    = (const int*)d_in[1];
    const float* Wl    = (const float*)d_in[2];
    const float* bl    = (const float*)d_in[3];
    const float* Wr    = (const float*)d_in[4];
    const float* br    = (const float*)d_in[5];
    const float* att   = (const float*)d_in[6];
    const float* bias  = (const float*)d_in[7];
    const float* gamma = (const float*)d_in[8];
    const float* beta  = (const float*)d_in[9];
    float* cur = (float*)d_out;

    char* ws = (char*)d_ws;
    size_t off = 0;
    auto alloc = [&](size_t bytes) -> void* {
        void* p = ws + off;
        off += (bytes + 255) & ~size_t(255);
        return p;
    };
    float* xl    = (float*)alloc((size_t)N_NODES * DIM * sizeof(float));
    float* xr    = (float*)alloc((size_t)N_NODES * DIM * sizeof(float));
    int* esrc    = (int*)alloc((size_t)N_EDGES * sizeof(int));
    int* rowptr  = (int*)alloc((size_t)(N_NODES + 1) * sizeof(int));
    int* deg     = (int*)alloc((size_t)N_NODES * sizeof(int));
    int* cnt     = (int*)alloc((size_t)N_NODES * sizeof(int));

    const int* srcArr = ei;
    const int* dstArr = ei + N_EDGES;

    hipMemsetAsync(deg, 0, N_NODES * sizeof(int), stream);
    hipMemsetAsync(cnt, 0, N_NODES * sizeof(int), stream);
    hipMemcpyAsync(cur, x, (size_t)N_NODES * DIM * sizeof(float),
                   hipMemcpyDeviceToDevice, stream);

    hist_kernel<<<(N_EDGES + 255) / 256, 256, 0, stream>>>(dstArr, deg);
    scan_kernel<<<1, 1024, 0, stream>>>(deg, rowptr);
    scatter_kernel<<<(N_EDGES + 255) / 256, 256, 0, stream>>>(srcArr, dstArr, rowptr, cnt, esrc);

    for (int l = 0; l < NLAYER; ++l) {
        gemm_kernel<<<(N_NODES + 63) / 64, 256, 0, stream>>>(
            cur, Wl + (size_t)l * DIM * DIM, bl + (size_t)l * DIM,
            Wr + (size_t)l * DIM * DIM, br + (size_t)l * DIM, xl, xr);
        agg_kernel<<<(N_NODES + 3) / 4, 256, 0, stream>>>(
            xl, xr, esrc, rowptr, att + (size_t)l * DIM, bias + (size_t)l * DIM,
            gamma + (size_t)l * DIM, beta + (size_t)l * DIM, cur);
    }
}

// Round 2
// 389.522 us; speedup vs baseline: 1.6812x; 1.6812x over previous
//
#include <hip/hip_runtime.h>
#include <hip/hip_bf16.h>
#include <math.h>

#define N_NODES 50000
#define N_EDGES 640000
#define DIM 128
#define NLAYER 3
#define NEG_SLOPE 0.2f
#define LN_EPS 1e-5f

typedef __attribute__((ext_vector_type(8))) short bf16x8;
typedef __attribute__((ext_vector_type(4))) float f32x4;

__device__ inline ushort f2b(float f) {
    __hip_bfloat16 h = __float2bfloat16(f);
    return *reinterpret_cast<ushort*>(&h);
}
__device__ inline float bf_lo(unsigned u) { return __uint_as_float(u << 16); }
__device__ inline float bf_hi(unsigned u) { return __uint_as_float(u & 0xffff0000u); }

// ---------------- converts ----------------

__global__ void convert_x(const float* __restrict__ x, ushort* __restrict__ xb) {
    int i = blockIdx.x * 256 + threadIdx.x;          // one float4 each
    if (i < N_NODES * DIM / 4) {
        float4 v = reinterpret_cast<const float4*>(x)[i];
        ushort4 o;
        o.x = f2b(v.x); o.y = f2b(v.y); o.z = f2b(v.z); o.w = f2b(v.w);
        reinterpret_cast<ushort4*>(xb)[i] = o;
    }
}

// Wt layout: [L][2][n=128][k=128] bf16 (n-major so B-frags are 16B contiguous)
__global__ void convert_w(const float* __restrict__ Wl, const float* __restrict__ Wr,
                          ushort* __restrict__ Wt) {
    int i = blockIdx.x * 256 + threadIdx.x;
    if (i >= NLAYER * 2 * DIM * DIM) return;
    int k = i & 127, n = (i >> 7) & 127, mat = (i >> 14) & 1, l = i >> 15;
    const float* W = mat ? Wr : Wl;
    Wt[i] = f2b(W[l * DIM * DIM + k * DIM + n]);
}

// ---------------- CSR build ----------------

__global__ void hist_kernel(const int* __restrict__ dst, int* __restrict__ deg) {
    int e = blockIdx.x * blockDim.x + threadIdx.x;
    if (e < N_EDGES) atomicAdd(&deg[dst[e]], 1);
}

__global__ __launch_bounds__(1024) void scan1(const int* __restrict__ deg,
                                              int* __restrict__ rowptr,
                                              int* __restrict__ bsum) {
    __shared__ int sd[1024];
    int t = threadIdx.x;
    int idx = blockIdx.x * 1024 + t;
    sd[t] = (idx < N_NODES) ? deg[idx] : 0;
    __syncthreads();
    for (int off = 1; off < 1024; off <<= 1) {
        int add = (t >= off) ? sd[t - off] : 0;
        __syncthreads();
        sd[t] += add;
        __syncthreads();
    }
    if (idx < N_NODES) rowptr[idx + 1] = sd[t];
    if (t == 1023) bsum[blockIdx.x] = sd[1023];
}

__global__ __launch_bounds__(1024) void scan2(int* __restrict__ rowptr,
                                              const int* __restrict__ bsum) {
    int t = threadIdx.x;
    int idx = blockIdx.x * 1024 + t;
    int carry = 0;
    for (int b = 0; b < (int)blockIdx.x; ++b) carry += bsum[b];
    if (idx == 0) rowptr[0] = 0;
    if (idx < N_NODES) rowptr[idx + 1] += carry;
}

__global__ void scatter_kernel(const int* __restrict__ src, const int* __restrict__ dst,
                               const int* __restrict__ rowptr, int* __restrict__ cnt,
                               int* __restrict__ esrc) {
    int e = blockIdx.x * blockDim.x + threadIdx.x;
    if (e < N_EDGES) {
        int d = dst[e];
        int pos = rowptr[d] + atomicAdd(&cnt[d], 1);
        esrc[pos] = src[e];
    }
}

// ---------------- MFMA GEMM: out = bf16(curb @ W + bias) ----------------
// block = 256 (4 waves, 2x2), tile 128 rows x 128 cols, K = 128, no LDS.
// blockIdx.y selects {Wl->xlb, Wr->xrb}.

__global__ __launch_bounds__(256) void gemm_mfma(
    const ushort* __restrict__ A,      // [N_NODES][128] bf16
    const ushort* __restrict__ Wt_l,   // [2][128n][128k] bf16
    const float* __restrict__ bl, const float* __restrict__ br,
    ushort* __restrict__ xlb, ushort* __restrict__ xrb)
{
    int mat = blockIdx.y;
    int rowbase = blockIdx.x * 128;
    int wid = threadIdx.x >> 6;
    int lane = threadIdx.x & 63;
    int wr = wid >> 1, wc = wid & 1;
    int m0 = rowbase + wr * 64, n0 = wc * 64;

    const ushort* W = Wt_l + mat * DIM * DIM;
    const float* bias = mat ? br : bl;
    ushort* out = mat ? xrb : xlb;

    int fr = lane & 15;    // frag row (m or n)
    int kg = lane >> 4;    // k-subgroup: k = kf*32 + kg*8 + i

    bf16x8 af[4][4], bfr[4][4];
    #pragma unroll
    for (int mf = 0; mf < 4; ++mf) {
        int row = m0 + mf * 16 + fr;
        if (row > N_NODES - 1) row = N_NODES - 1;
        const ushort* p = A + (size_t)row * DIM + kg * 8;
        #pragma unroll
        for (int kf = 0; kf < 4; ++kf)
            af[mf][kf] = *reinterpret_cast<const bf16x8*>(p + kf * 32);
    }
    #pragma unroll
    for (int nf = 0; nf < 4; ++nf) {
        const ushort* p = W + (size_t)(n0 + nf * 16 + fr) * DIM + kg * 8;
        #pragma unroll
        for (int kf = 0; kf < 4; ++kf)
            bfr[nf][kf] = *reinterpret_cast<const bf16x8*>(p + kf * 32);
    }

    f32x4 acc[4][4];
    #pragma unroll
    for (int mf = 0; mf < 4; ++mf)
        #pragma unroll
        for (int nf = 0; nf < 4; ++nf)
            acc[mf][nf] = (f32x4){0.f, 0.f, 0.f, 0.f};

    #pragma unroll
    for (int kf = 0; kf < 4; ++kf)
        #pragma unroll
        for (int mf = 0; mf < 4; ++mf)
            #pragma unroll
            for (int nf = 0; nf < 4; ++nf)
                acc[mf][nf] = __builtin_amdgcn_mfma_f32_16x16x32_bf16(
                    af[mf][kf], bfr[nf][kf], acc[mf][nf], 0, 0, 0);

    int col = lane & 15;
    int r4 = lane >> 4;
    #pragma unroll
    for (int mf = 0; mf < 4; ++mf) {
        #pragma unroll
        for (int nf = 0; nf < 4; ++nf) {
            int n = n0 + nf * 16 + col;
            float b = bias[n];
            #pragma unroll
            for (int r = 0; r < 4; ++r) {
                int row = m0 + mf * 16 + r4 * 4 + r;
                if (row < N_NODES)
                    out[(size_t)row * DIM + n] = f2b(acc[mf][nf][r] + b);
            }
        }
    }
}

// ---------------- fused edge aggregation + softmax + bias/relu + LN + residual ----
// one wave per dst node; lane l owns channels 2l, 2l+1. bf16 gathers, no-max exp.

__global__ __launch_bounds__(256) void agg_kernel(
    const unsigned* __restrict__ xlb2,   // [N][64] packed bf16x2
    const unsigned* __restrict__ xrb2,
    const int* __restrict__ esrc, const int* __restrict__ rowptr,
    const float* __restrict__ att, const float* __restrict__ bias,
    const float* __restrict__ gamma, const float* __restrict__ beta,
    float* __restrict__ cur, unsigned* __restrict__ curb, int write_b)
{
    int node = blockIdx.x * 4 + (threadIdx.x >> 6);
    int lane = threadIdx.x & 63;
    if (node >= N_NODES) return;

    unsigned xru = xrb2[node * 64 + lane];
    float xrx = bf_lo(xru), xry = bf_hi(xru);
    float2 att2 = *reinterpret_cast<const float2*>(&att[2 * lane]);

    float s = 0.f, ox = 0.f, oy = 0.f;
    int e0 = rowptr[node], e1 = rowptr[node + 1];
    int ebase = e0;
    int j64 = (e0 + lane < e1) ? esrc[e0 + lane] : 0;

    for (int e = e0; e < e1; ++e) {
        int k = e - ebase;
        if (k == 64) {
            ebase = e;
            j64 = (ebase + lane < e1) ? esrc[ebase + lane] : 0;
            k = 0;
        }
        int j = __shfl(j64, k);
        unsigned u = xlb2[j * 64 + lane];
        float vx = bf_lo(u), vy = bf_hi(u);
        float tx = vx + xrx, ty = vy + xry;
        tx = tx > 0.f ? tx : NEG_SLOPE * tx;
        ty = ty > 0.f ? ty : NEG_SLOPE * ty;
        float p = tx * att2.x + ty * att2.y;
        p += __shfl_xor(p, 1);
        p += __shfl_xor(p, 2);
        p += __shfl_xor(p, 4);
        p += __shfl_xor(p, 8);
        float w = __expf(p);    // logits bounded (~|p|<10): no max-shift needed
        s += w;
        ox += w * vx;
        oy += w * vy;
    }

    float inv = 1.f / (s + 1e-16f);
    float2 b2 = *reinterpret_cast<const float2*>(&bias[2 * lane]);
    float gx = fmaxf(ox * inv + b2.x, 0.f);
    float gy = fmaxf(oy * inv + b2.y, 0.f);

    float sum = gx + gy;
    #pragma unroll
    for (int off = 1; off < 64; off <<= 1) sum += __shfl_xor(sum, off);
    float mu = sum * (1.f / 128.f);
    float dx = gx - mu, dy = gy - mu;
    float ss = dx * dx + dy * dy;
    #pragma unroll
    for (int off = 1; off < 64; off <<= 1) ss += __shfl_xor(ss, off);
    float rstd = rsqrtf(ss * (1.f / 128.f) + LN_EPS);

    float2 g2  = *reinterpret_cast<const float2*>(&gamma[2 * lane]);
    float2 be2 = *reinterpret_cast<const float2*>(&beta[2 * lane]);
    float2 c2  = *reinterpret_cast<const float2*>(&cur[node * DIM + 2 * lane]);
    float yx = dx * rstd * g2.x + be2.x + c2.x;
    float yy = dy * rstd * g2.y + be2.y + c2.y;
    *reinterpret_cast<float2*>(&cur[node * DIM + 2 * lane]) = make_float2(yx, yy);
    if (write_b)
        curb[node * 64 + lane] = (unsigned)f2b(yx) | ((unsigned)f2b(yy) << 16);
}

// ---------------- launch ----------------

extern "C" void kernel_launch(void* const* d_in, const int* in_sizes, int n_in,
                              void* d_out, int out_size, void* d_ws, size_t ws_size,
                              hipStream_t stream) {
    const float* x     = (const float*)d_in[0];
    const int*   ei    = (const int*)d_in[1];
    const float* Wl    = (const float*)d_in[2];
    const float* bl    = (const float*)d_in[3];
    const float* Wr    = (const float*)d_in[4];
    const float* br    = (const float*)d_in[5];
    const float* att   = (const float*)d_in[6];
    const float* bias  = (const float*)d_in[7];
    const float* gamma = (const float*)d_in[8];
    const float* beta  = (const float*)d_in[9];
    float* cur = (float*)d_out;

    char* ws = (char*)d_ws;
    size_t off = 0;
    auto alloc = [&](size_t bytes) -> void* {
        void* p = ws + off;
        off += (bytes + 255) & ~size_t(255);
        return p;
    };
    ushort* xlb   = (ushort*)alloc((size_t)N_NODES * DIM * 2);
    ushort* xrb   = (ushort*)alloc((size_t)N_NODES * DIM * 2);
    ushort* curb  = (ushort*)alloc((size_t)N_NODES * DIM * 2);
    ushort* Wt    = (ushort*)alloc((size_t)NLAYER * 2 * DIM * DIM * 2);
    int* esrc     = (int*)alloc((size_t)N_EDGES * 4);
    int* rowptr   = (int*)alloc((size_t)(N_NODES + 1) * 4);
    int* deg      = (int*)alloc((size_t)N_NODES * 4);
    int* cnt      = (int*)alloc((size_t)N_NODES * 4);
    int* bsum     = (int*)alloc(64 * 4);

    const int* srcArr = ei;
    const int* dstArr = ei + N_EDGES;

    hipMemsetAsync(deg, 0, N_NODES * 4, stream);
    hipMemsetAsync(cnt, 0, N_NODES * 4, stream);
    hipMemcpyAsync(cur, x, (size_t)N_NODES * DIM * sizeof(float),
                   hipMemcpyDeviceToDevice, stream);

    convert_x<<<(N_NODES * DIM / 4 + 255) / 256, 256, 0, stream>>>(x, curb);
    convert_w<<<(NLAYER * 2 * DIM * DIM + 255) / 256, 256, 0, stream>>>(Wl, Wr, Wt);

    hist_kernel<<<(N_EDGES + 255) / 256, 256, 0, stream>>>(dstArr, deg);
    int nscan = (N_NODES + 1023) / 1024;
    scan1<<<nscan, 1024, 0, stream>>>(deg, rowptr, bsum);
    scan2<<<nscan, 1024, 0, stream>>>(rowptr, bsum);
    scatter_kernel<<<(N_EDGES + 255) / 256, 256, 0, stream>>>(srcArr, dstArr, rowptr, cnt, esrc);

    for (int l = 0; l < NLAYER; ++l) {
        gemm_mfma<<<dim3((N_NODES + 127) / 128, 2), 256, 0, stream>>>(
            curb, Wt + (size_t)l * 2 * DIM * DIM,
            bl + (size_t)l * DIM, br + (size_t)l * DIM, xlb, xrb);
        agg_kernel<<<(N_NODES + 3) / 4, 256, 0, stream>>>(
            (const unsigned*)xlb, (const unsigned*)xrb, esrc, rowptr,
            att + (size_t)l * DIM, bias + (size_t)l * DIM,
            gamma + (size_t)l * DIM, beta + (size_t)l * DIM,
            cur, (unsigned*)curb, l < NLAYER - 1 ? 1 : 0);
    }
}

// Round 3
// 312.314 us; speedup vs baseline: 2.0968x; 1.2472x over previous
//
#include <hip/hip_runtime.h>
#include <hip/hip_bf16.h>
#include <math.h>

#define N_NODES 50000
#define N_EDGES 640000
#define DIM 128
#define NLAYER 3
#define NEG_SLOPE 0.2f
#define LN_EPS 1e-5f

typedef __attribute__((ext_vector_type(8))) short bf16x8;
typedef __attribute__((ext_vector_type(4))) float f32x4;

__device__ inline ushort f2b(float f) {
    __hip_bfloat16 h = __float2bfloat16(f);
    return *reinterpret_cast<ushort*>(&h);
}
__device__ inline float bf_lo(unsigned u) { return __uint_as_float(u << 16); }
__device__ inline float bf_hi(unsigned u) { return __uint_as_float(u & 0xffff0000u); }
__device__ inline float lrelu(float t) { return t > 0.f ? t : NEG_SLOPE * t; }

// ---------------- fused init: residual copy + bf16 convert + zero deg/cnt ----------------

__global__ __launch_bounds__(256) void init_kernel(const float* __restrict__ x,
                                                   float* __restrict__ cur,
                                                   unsigned* __restrict__ curb,
                                                   int* __restrict__ deg,
                                                   int* __restrict__ cnt) {
    int i = blockIdx.x * 256 + threadIdx.x;   // one float2 / packed-bf16x2 each
    if (i < N_NODES * 64) {
        float2 v = reinterpret_cast<const float2*>(x)[i];
        reinterpret_cast<float2*>(cur)[i] = v;
        curb[i] = (unsigned)f2b(v.x) | ((unsigned)f2b(v.y) << 16);
    }
    if (i < N_NODES) { deg[i] = 0; cnt[i] = 0; }
}

// Wt layout: [L][2][n=128][k=128] bf16 (n-major so B-frags are 16B contiguous)
__global__ void convert_w(const float* __restrict__ Wl, const float* __restrict__ Wr,
                          ushort* __restrict__ Wt) {
    int i = blockIdx.x * 256 + threadIdx.x;
    if (i >= NLAYER * 2 * DIM * DIM) return;
    int k = i & 127, n = (i >> 7) & 127, mat = (i >> 14) & 1, l = i >> 15;
    const float* W = mat ? Wr : Wl;
    Wt[i] = f2b(W[l * DIM * DIM + k * DIM + n]);
}

// ---------------- CSR build ----------------

__global__ void hist_kernel(const int* __restrict__ dst, int* __restrict__ deg) {
    int e = blockIdx.x * blockDim.x + threadIdx.x;
    if (e < N_EDGES) atomicAdd(&deg[dst[e]], 1);
}

__global__ __launch_bounds__(1024) void scan1(const int* __restrict__ deg,
                                              int* __restrict__ rowptr,
                                              int* __restrict__ bsum) {
    __shared__ int sd[1024];
    int t = threadIdx.x;
    int idx = blockIdx.x * 1024 + t;
    sd[t] = (idx < N_NODES) ? deg[idx] : 0;
    __syncthreads();
    for (int off = 1; off < 1024; off <<= 1) {
        int add = (t >= off) ? sd[t - off] : 0;
        __syncthreads();
        sd[t] += add;
        __syncthreads();
    }
    if (idx < N_NODES) rowptr[idx + 1] = sd[t];
    if (t == 1023) bsum[blockIdx.x] = sd[1023];
}

__global__ __launch_bounds__(1024) void scan2(int* __restrict__ rowptr,
                                              const int* __restrict__ bsum) {
    int t = threadIdx.x;
    int idx = blockIdx.x * 1024 + t;
    int carry = 0;
    for (int b = 0; b < (int)blockIdx.x; ++b) carry += bsum[b];
    if (idx == 0) rowptr[0] = 0;
    if (idx < N_NODES) rowptr[idx + 1] += carry;
}

// esrc holds BYTE offsets (src*256) into the packed bf16 node rows.
__global__ void scatter_kernel(const int* __restrict__ src, const int* __restrict__ dst,
                               const int* __restrict__ rowptr, int* __restrict__ cnt,
                               int* __restrict__ esrc) {
    int e = blockIdx.x * blockDim.x + threadIdx.x;
    if (e < N_EDGES) {
        int d = dst[e];
        int pos = rowptr[d] + atomicAdd(&cnt[d], 1);
        esrc[pos] = src[e] << 8;
    }
}

// ---------------- MFMA GEMM: out = bf16(curb @ W + bias) ----------------

__global__ __launch_bounds__(256) void gemm_mfma(
    const ushort* __restrict__ A,      // [N_NODES][128] bf16
    const ushort* __restrict__ Wt_l,   // [2][128n][128k] bf16
    const float* __restrict__ bl, const float* __restrict__ br,
    ushort* __restrict__ xlb, ushort* __restrict__ xrb)
{
    int mat = blockIdx.y;
    int rowbase = blockIdx.x * 128;
    int wid = threadIdx.x >> 6;
    int lane = threadIdx.x & 63;
    int wr = wid >> 1, wc = wid & 1;
    int m0 = rowbase + wr * 64, n0 = wc * 64;

    const ushort* W = Wt_l + mat * DIM * DIM;
    const float* bias = mat ? br : bl;
    ushort* out = mat ? xrb : xlb;

    int fr = lane & 15;    // frag row (m or n)
    int kg = lane >> 4;    // k-subgroup: k = kf*32 + kg*8 + i

    bf16x8 af[4][4], bfr[4][4];
    #pragma unroll
    for (int mf = 0; mf < 4; ++mf) {
        int row = m0 + mf * 16 + fr;
        if (row > N_NODES - 1) row = N_NODES - 1;
        const ushort* p = A + (size_t)row * DIM + kg * 8;
        #pragma unroll
        for (int kf = 0; kf < 4; ++kf)
            af[mf][kf] = *reinterpret_cast<const bf16x8*>(p + kf * 32);
    }
    #pragma unroll
    for (int nf = 0; nf < 4; ++nf) {
        const ushort* p = W + (size_t)(n0 + nf * 16 + fr) * DIM + kg * 8;
        #pragma unroll
        for (int kf = 0; kf < 4; ++kf)
            bfr[nf][kf] = *reinterpret_cast<const bf16x8*>(p + kf * 32);
    }

    f32x4 acc[4][4];
    #pragma unroll
    for (int mf = 0; mf < 4; ++mf)
        #pragma unroll
        for (int nf = 0; nf < 4; ++nf)
            acc[mf][nf] = (f32x4){0.f, 0.f, 0.f, 0.f};

    #pragma unroll
    for (int kf = 0; kf < 4; ++kf)
        #pragma unroll
        for (int mf = 0; mf < 4; ++mf)
            #pragma unroll
            for (int nf = 0; nf < 4; ++nf)
                acc[mf][nf] = __builtin_amdgcn_mfma_f32_16x16x32_bf16(
                    af[mf][kf], bfr[nf][kf], acc[mf][nf], 0, 0, 0);

    int col = lane & 15;
    int r4 = lane >> 4;
    #pragma unroll
    for (int mf = 0; mf < 4; ++mf) {
        #pragma unroll
        for (int nf = 0; nf < 4; ++nf) {
            int n = n0 + nf * 16 + col;
            float b = bias[n];
            #pragma unroll
            for (int r = 0; r < 4; ++r) {
                int row = m0 + mf * 16 + r4 * 4 + r;
                if (row < N_NODES)
                    out[(size_t)row * DIM + n] = f2b(acc[mf][nf][r] + b);
            }
        }
    }
}

// ---------------- fused aggregation, unroll-4 for MLP ----------------
// one wave per dst node; lane l owns channels 2l, 2l+1.

__global__ __launch_bounds__(256) void agg_kernel(
    const unsigned* __restrict__ xlb2,   // [N][64] packed bf16x2
    const unsigned* __restrict__ xrb2,
    const int* __restrict__ esrc,        // byte offsets (src*256)
    const int* __restrict__ rowptr,
    const float* __restrict__ att, const float* __restrict__ bias,
    const float* __restrict__ gamma, const float* __restrict__ beta,
    float* __restrict__ cur, unsigned* __restrict__ curb, int write_b)
{
    int node = blockIdx.x * 4 + (threadIdx.x >> 6);
    int lane = threadIdx.x & 63;
    if (node >= N_NODES) return;

    unsigned xru = xrb2[node * 64 + lane];
    float xrx = bf_lo(xru), xry = bf_hi(xru);
    float2 att2 = *reinterpret_cast<const float2*>(&att[2 * lane]);

    const char* xb = (const char*)xlb2;
    int laneoff = lane << 2;

    float s = 0.f, ox = 0.f, oy = 0.f;
    int e0 = rowptr[node], e1 = rowptr[node + 1];

    for (int cb = e0; cb < e1; cb += 64) {
        int rem = e1 - cb;
        int cnt = rem < 64 ? rem : 64;
        int jv = (cb + lane < e1) ? esrc[cb + lane] : 0;
        int k = 0;
        for (; k + 4 <= cnt; k += 4) {
            int j0 = __shfl(jv, k);
            int j1 = __shfl(jv, k + 1);
            int j2 = __shfl(jv, k + 2);
            int j3 = __shfl(jv, k + 3);
            unsigned u0 = *(const unsigned*)(xb + j0 + laneoff);
            unsigned u1 = *(const unsigned*)(xb + j1 + laneoff);
            unsigned u2 = *(const unsigned*)(xb + j2 + laneoff);
            unsigned u3 = *(const unsigned*)(xb + j3 + laneoff);
            float vx0 = bf_lo(u0), vy0 = bf_hi(u0);
            float vx1 = bf_lo(u1), vy1 = bf_hi(u1);
            float vx2 = bf_lo(u2), vy2 = bf_hi(u2);
            float vx3 = bf_lo(u3), vy3 = bf_hi(u3);
            float p0 = lrelu(vx0 + xrx) * att2.x + lrelu(vy0 + xry) * att2.y;
            float p1 = lrelu(vx1 + xrx) * att2.x + lrelu(vy1 + xry) * att2.y;
            float p2 = lrelu(vx2 + xrx) * att2.x + lrelu(vy2 + xry) * att2.y;
            float p3 = lrelu(vx3 + xrx) * att2.x + lrelu(vy3 + xry) * att2.y;
            p0 += __shfl_xor(p0, 1); p1 += __shfl_xor(p1, 1);
            p2 += __shfl_xor(p2, 1); p3 += __shfl_xor(p3, 1);
            p0 += __shfl_xor(p0, 2); p1 += __shfl_xor(p1, 2);
            p2 += __shfl_xor(p2, 2); p3 += __shfl_xor(p3, 2);
            p0 += __shfl_xor(p0, 4); p1 += __shfl_xor(p1, 4);
            p2 += __shfl_xor(p2, 4); p3 += __shfl_xor(p3, 4);
            p0 += __shfl_xor(p0, 8); p1 += __shfl_xor(p1, 8);
            p2 += __shfl_xor(p2, 8); p3 += __shfl_xor(p3, 8);
            float w0 = __expf(p0), w1 = __expf(p1);
            float w2 = __expf(p2), w3 = __expf(p3);
            s += w0; ox = fmaf(w0, vx0, ox); oy = fmaf(w0, vy0, oy);
            s += w1; ox = fmaf(w1, vx1, ox); oy = fmaf(w1, vy1, oy);
            s += w2; ox = fmaf(w2, vx2, ox); oy = fmaf(w2, vy2, oy);
            s += w3; ox = fmaf(w3, vx3, ox); oy = fmaf(w3, vy3, oy);
        }
        for (; k < cnt; ++k) {
            int j = __shfl(jv, k);
            unsigned u = *(const unsigned*)(xb + j + laneoff);
            float vx = bf_lo(u), vy = bf_hi(u);
            float p = lrelu(vx + xrx) * att2.x + lrelu(vy + xry) * att2.y;
            p += __shfl_xor(p, 1);
            p += __shfl_xor(p, 2);
            p += __shfl_xor(p, 4);
            p += __shfl_xor(p, 8);
            float w = __expf(p);
            s += w; ox = fmaf(w, vx, ox); oy = fmaf(w, vy, oy);
        }
    }

    float inv = 1.f / (s + 1e-16f);
    float2 b2 = *reinterpret_cast<const float2*>(&bias[2 * lane]);
    float gx = fmaxf(ox * inv + b2.x, 0.f);
    float gy = fmaxf(oy * inv + b2.y, 0.f);

    float sum = gx + gy;
    #pragma unroll
    for (int off = 1; off < 64; off <<= 1) sum += __shfl_xor(sum, off);
    float mu = sum * (1.f / 128.f);
    float dx = gx - mu, dy = gy - mu;
    float ss = dx * dx + dy * dy;
    #pragma unroll
    for (int off = 1; off < 64; off <<= 1) ss += __shfl_xor(ss, off);
    float rstd = rsqrtf(ss * (1.f / 128.f) + LN_EPS);

    float2 g2  = *reinterpret_cast<const float2*>(&gamma[2 * lane]);
    float2 be2 = *reinterpret_cast<const float2*>(&beta[2 * lane]);
    float2 c2  = *reinterpret_cast<const float2*>(&cur[node * DIM + 2 * lane]);
    float yx = dx * rstd * g2.x + be2.x + c2.x;
    float yy = dy * rstd * g2.y + be2.y + c2.y;
    *reinterpret_cast<float2*>(&cur[node * DIM + 2 * lane]) = make_float2(yx, yy);
    if (write_b)
        curb[node * 64 + lane] = (unsigned)f2b(yx) | ((unsigned)f2b(yy) << 16);
}

// ---------------- launch ----------------

extern "C" void kernel_launch(void* const* d_in, const int* in_sizes, int n_in,
                              void* d_out, int out_size, void* d_ws, size_t ws_size,
                              hipStream_t stream) {
    const float* x     = (const float*)d_in[0];
    const int*   ei    = (const int*)d_in[1];
    const float* Wl    = (const float*)d_in[2];
    const float* bl    = (const float*)d_in[3];
    const float* Wr    = (const float*)d_in[4];
    const float* br    = (const float*)d_in[5];
    const float* att   = (const float*)d_in[6];
    const float* bias  = (const float*)d_in[7];
    const float* gamma = (const float*)d_in[8];
    const float* beta  = (const float*)d_in[9];
    float* cur = (float*)d_out;

    char* ws = (char*)d_ws;
    size_t off = 0;
    auto alloc = [&](size_t bytes) -> void* {
        void* p = ws + off;
        off += (bytes + 255) & ~size_t(255);
        return p;
    };
    ushort* xlb   = (ushort*)alloc((size_t)N_NODES * DIM * 2);
    ushort* xrb   = (ushort*)alloc((size_t)N_NODES * DIM * 2);
    ushort* curb  = (ushort*)alloc((size_t)N_NODES * DIM * 2);
    ushort* Wt    = (ushort*)alloc((size_t)NLAYER * 2 * DIM * DIM * 2);
    int* esrc     = (int*)alloc((size_t)N_EDGES * 4);
    int* rowptr   = (int*)alloc((size_t)(N_NODES + 1) * 4);
    int* deg      = (int*)alloc((size_t)N_NODES * 4);
    int* cnt      = (int*)alloc((size_t)N_NODES * 4);
    int* bsum     = (int*)alloc(64 * 4);

    const int* srcArr = ei;
    const int* dstArr = ei + N_EDGES;

    init_kernel<<<(N_NODES * 64 + 255) / 256, 256, 0, stream>>>(x, cur, (unsigned*)curb, deg, cnt);
    convert_w<<<(NLAYER * 2 * DIM * DIM + 255) / 256, 256, 0, stream>>>(Wl, Wr, Wt);

    hist_kernel<<<(N_EDGES + 255) / 256, 256, 0, stream>>>(dstArr, deg);
    int nscan = (N_NODES + 1023) / 1024;
    scan1<<<nscan, 1024, 0, stream>>>(deg, rowptr, bsum);
    scan2<<<nscan, 1024, 0, stream>>>(rowptr, bsum);
    scatter_kernel<<<(N_EDGES + 255) / 256, 256, 0, stream>>>(srcArr, dstArr, rowptr, cnt, esrc);

    for (int l = 0; l < NLAYER; ++l) {
        gemm_mfma<<<dim3((N_NODES + 127) / 128, 2), 256, 0, stream>>>(
            curb, Wt + (size_t)l * 2 * DIM * DIM,
            bl + (size_t)l * DIM, br + (size_t)l * DIM, xlb, xrb);
        agg_kernel<<<(N_NODES + 3) / 4, 256, 0, stream>>>(
            (const unsigned*)xlb, (const unsigned*)xrb, esrc, rowptr,
            att + (size_t)l * DIM, bias + (size_t)l * DIM,
            gamma + (size_t)l * DIM, beta + (size_t)l * DIM,
            cur, (unsigned*)curb, l < NLAYER - 1 ? 1 : 0);
    }
}